// Round 4
// baseline (336.391 us; speedup 1.0000x reference)
//
#include <hip/hip_runtime.h>

typedef __bf16 bf16;
typedef __bf16 bf16x4 __attribute__((ext_vector_type(4)));
typedef __bf16 bf16x8 __attribute__((ext_vector_type(8)));
typedef float f32x4 __attribute__((ext_vector_type(4)));

#define MFMA16(a, b, c) __builtin_amdgcn_mfma_f32_16x16x32_bf16(a, b, c, 0, 0, 0)

// fp32 -> bf16 bulk convert (n4 = count of float4 groups; sizes all %4==0)
__global__ void cvt(const float* __restrict__ in, bf16* __restrict__ out,
                    int n4) {
  const int i = blockIdx.x * blockDim.x + threadIdx.x;
  if (i < n4) {
    const float4 v = ((const float4*)in)[i];
    bf16x4 o;
    o[0] = (bf16)v.x; o[1] = (bf16)v.y; o[2] = (bf16)v.z; o[3] = (bf16)v.w;
    ((bf16x4*)out)[i] = o;
  }
}

// C = A[M][K] * B[N][K]^T + bias[N]; A,B bf16 (pre-converted), fp32 accum.
// MODE 0: write float C (stride N) -> d_out.
// MODE 1: QKV epilogue (N=3072), bf16 out: col<1024 -> Qb[t][col];
//         col<2048 -> Kb[t][col-1024]; col>=2048 -> VT[b][h][dh][t].
template <int MODE>
__global__ __launch_bounds__(256, 2) void gemm_bt(
    const bf16* __restrict__ A, const bf16* __restrict__ B,
    const float* __restrict__ bias, float* __restrict__ Cf,
    bf16* __restrict__ Qb, bf16* __restrict__ Kb, bf16* __restrict__ VT,
    int N, int K) {
  __shared__ bf16 As[128][64];
  __shared__ bf16 Bs[128][64];
  const int tid = threadIdx.x;
  const int w = tid >> 6, lane = tid & 63;
  const int l15 = lane & 15, quad = lane >> 4;
  const int bn = blockIdx.x, bm = blockIdx.y;
  const int wm = (w >> 1) * 64, wn = (w & 1) * 64;

  const bf16* Abase = A + (size_t)(bm * 128) * K;
  const bf16* Bbase = B + (size_t)(bn * 128) * K;

  f32x4 acc[4][4] = {};

  for (int k0 = 0; k0 < K; k0 += 64) {
#pragma unroll
    for (int c = tid; c < 1024; c += 256) {
      const int row = c >> 3, col = (c & 7) << 3;
      *(bf16x8*)&As[row][col] =
          *(const bf16x8*)&Abase[(size_t)row * K + k0 + col];
      *(bf16x8*)&Bs[row][col] =
          *(const bf16x8*)&Bbase[(size_t)row * K + k0 + col];
    }
    __syncthreads();
#pragma unroll
    for (int kk = 0; kk < 64; kk += 32) {
      bf16x8 am[4], bnf[4];
#pragma unroll
      for (int i = 0; i < 4; ++i)
        am[i] = *(const bf16x8*)&As[wm + i * 16 + l15][kk + quad * 8];
#pragma unroll
      for (int j = 0; j < 4; ++j)
        bnf[j] = *(const bf16x8*)&Bs[wn + j * 16 + l15][kk + quad * 8];
#pragma unroll
      for (int i = 0; i < 4; ++i)
#pragma unroll
        for (int j = 0; j < 4; ++j)
          acc[i][j] = MFMA16(am[i], bnf[j], acc[i][j]);
    }
    __syncthreads();
  }

  // epilogue: C/D layout col=lane&15, row=quad*4+reg
#pragma unroll
  for (int j = 0; j < 4; ++j) {
    const int gcol = bn * 128 + wn + j * 16 + l15;
    const float bv = bias[gcol];
#pragma unroll
    for (int i = 0; i < 4; ++i) {
#pragma unroll
      for (int r = 0; r < 4; ++r) {
        const int grow = bm * 128 + wm + i * 16 + quad * 4 + r;
        const float v = acc[i][j][r] + bv;
        if (MODE == 0) {
          Cf[(size_t)grow * N + gcol] = v;
        } else {
          if (gcol < 1024) {
            Qb[(size_t)grow * 1024 + gcol] = (bf16)v;
          } else if (gcol < 2048) {
            Kb[(size_t)grow * 1024 + (gcol - 1024)] = (bf16)v;
          } else {
            const int b = grow >> 11, t = grow & 2047;
            const int hh = (gcol >> 6) & 15, dh = gcol & 63;
            VT[(size_t)((b * 16 + hh) * 64 + dh) * 2048 + t] = (bf16)v;
          }
        }
      }
    }
  }
}

// Flash attention: one block per (b, h, 64-row q tile). 4 waves x 16 q rows.
// Qb/Kb: [token][1024] (head h at col h*64). VT: [b][h][dh][2048].
__global__ __launch_bounds__(256, 2) void attn(const bf16* __restrict__ Qb,
                                               const bf16* __restrict__ Kb,
                                               const bf16* __restrict__ VT,
                                               bf16* __restrict__ CTX) {
  __shared__ bf16 Qs[64][64];
  __shared__ bf16 Ks[64][64];
  __shared__ bf16 Vs[64][64];  // V^T tile: [dh][key]
  __shared__ bf16 Ps[64][64];
  const int tid = threadIdx.x, w = tid >> 6, lane = tid & 63;
  const int l15 = lane & 15, quad = lane >> 4;
  const int blk = blockIdx.x;
  const int qt = blk & 31, h = (blk >> 5) & 15, b = blk >> 9;
  const int q0 = qt * 64;

  const bf16* qbase = Qb + (size_t)(b * 2048 + q0) * 1024 + h * 64;
  const bf16* kbase = Kb + (size_t)(b * 2048) * 1024 + h * 64;
  const bf16* vbase = VT + (size_t)((b * 16 + h) * 64) * 2048;

#pragma unroll
  for (int c = tid; c < 512; c += 256) {
    const int row = c >> 3, col = (c & 7) << 3;
    *(bf16x8*)&Qs[row][col] = *(const bf16x8*)&qbase[(size_t)row * 1024 + col];
  }

  float m_run[4], l_run[4];
#pragma unroll
  for (int r = 0; r < 4; ++r) { m_run[r] = -1e30f; l_run[r] = 0.f; }
  f32x4 o[4] = {};

  for (int kt = 0; kt < 2048; kt += 64) {
#pragma unroll
    for (int c = tid; c < 512; c += 256) {
      const int row = c >> 3, col = (c & 7) << 3;
      *(bf16x8*)&Ks[row][col] =
          *(const bf16x8*)&kbase[(size_t)(kt + row) * 1024 + col];
      *(bf16x8*)&Vs[row][col] =
          *(const bf16x8*)&vbase[(size_t)row * 2048 + kt + col];
    }
    __syncthreads();

    // S = Q K^T for this wave's 16 q rows x 64 keys
    f32x4 s[4] = {};
#pragma unroll
    for (int kk = 0; kk < 64; kk += 32) {
      const bf16x8 aq = *(const bf16x8*)&Qs[w * 16 + l15][kk + quad * 8];
#pragma unroll
      for (int j = 0; j < 4; ++j) {
        const bf16x8 bk = *(const bf16x8*)&Ks[j * 16 + l15][kk + quad * 8];
        s[j] = MFMA16(aq, bk, s[j]);
      }
    }

    // online softmax; q row quad*4+r: 64 keys = 4 regs x 16 lanes of this quad
    float alpha[4];
#pragma unroll
    for (int r = 0; r < 4; ++r) {
      float v = fmaxf(fmaxf(s[0][r], s[1][r]), fmaxf(s[2][r], s[3][r])) * 0.125f;
#pragma unroll
      for (int off = 1; off < 16; off <<= 1) v = fmaxf(v, __shfl_xor(v, off));
      const float mnew = fmaxf(m_run[r], v);
      alpha[r] = __expf(m_run[r] - mnew);
      float sum = 0.f;
#pragma unroll
      for (int j = 0; j < 4; ++j) {
        const float p = __expf(s[j][r] * 0.125f - mnew);
        s[j][r] = p;
        sum += p;
      }
#pragma unroll
      for (int off = 1; off < 16; off <<= 1) sum += __shfl_xor(sum, off);
      l_run[r] = l_run[r] * alpha[r] + sum;
      m_run[r] = mnew;
    }

    // P: C-layout -> LDS -> A-layout (rows wave-private), rescale O
#pragma unroll
    for (int j = 0; j < 4; ++j)
#pragma unroll
      for (int r = 0; r < 4; ++r) {
        Ps[w * 16 + quad * 4 + r][j * 16 + l15] = (bf16)s[j][r];
        o[j][r] *= alpha[r];
      }
    __syncthreads();

    // O += P * V  (V^T tile [dh][key] -> contiguous B frags)
#pragma unroll
    for (int kk = 0; kk < 64; kk += 32) {
      const bf16x8 ap = *(const bf16x8*)&Ps[w * 16 + l15][kk + quad * 8];
#pragma unroll
      for (int j = 0; j < 4; ++j) {
        const bf16x8 bv = *(const bf16x8*)&Vs[j * 16 + l15][kk + quad * 8];
        o[j] = MFMA16(ap, bv, o[j]);
      }
    }
    __syncthreads();
  }

#pragma unroll
  for (int r = 0; r < 4; ++r) {
    const float inv = 1.f / l_run[r];
    const size_t rowoff =
        (size_t)(b * 2048 + q0 + w * 16 + quad * 4 + r) * 1024 + h * 64;
#pragma unroll
    for (int j = 0; j < 4; ++j)
      CTX[rowoff + j * 16 + l15] = (bf16)(o[j][r] * inv);
  }
}

extern "C" void kernel_launch(void* const* d_in, const int* in_sizes, int n_in,
                              void* d_out, int out_size, void* d_ws,
                              size_t ws_size, hipStream_t stream) {
  const float* x = (const float*)d_in[0];      // [2,2048,1024] fp32
  const float* qkv_w = (const float*)d_in[1];  // [3072,1024] fp32
  const float* qkv_b = (const float*)d_in[2];  // [3072] fp32
  const float* out_w = (const float*)d_in[3];  // [1024,1024] fp32
  const float* out_b = (const float*)d_in[4];  // [1024] fp32
  float* out = (float*)d_out;                  // [2,2048,1024] fp32

  // ws (bf16): xb 8MB | wqkv 6MB | wout 2MB | qb 8 | kb 8 | vt 8 | ctx 8 = 48MB
  bf16* xb = (bf16*)d_ws;                   // [4096][1024]
  bf16* wqkv = xb + (size_t)4096 * 1024;    // [3072][1024]
  bf16* wout = wqkv + (size_t)3072 * 1024;  // [1024][1024]
  bf16* qb = wout + (size_t)1024 * 1024;    // [4096][1024]
  bf16* kb = qb + (size_t)4096 * 1024;      // [4096][1024]
  bf16* vt = kb + (size_t)4096 * 1024;      // [2][16][64][2048]
  bf16* ctx = vt + (size_t)4096 * 1024;     // [4096][1024]

  cvt<<<(4096 * 1024 / 4 + 255) / 256, 256, 0, stream>>>(x, xb, 4096 * 1024 / 4);
  cvt<<<(3072 * 1024 / 4 + 255) / 256, 256, 0, stream>>>(qkv_w, wqkv,
                                                         3072 * 1024 / 4);
  cvt<<<(1024 * 1024 / 4 + 255) / 256, 256, 0, stream>>>(out_w, wout,
                                                         1024 * 1024 / 4);

  gemm_bt<1><<<dim3(24, 32), 256, 0, stream>>>(xb, wqkv, qkv_b, nullptr, qb,
                                               kb, vt, 3072, 1024);
  attn<<<1024, 256, 0, stream>>>(qb, kb, vt, ctx);
  gemm_bt<0><<<dim3(8, 32), 256, 0, stream>>>(ctx, wout, out_b, out, nullptr,
                                              nullptr, nullptr, 1024, 1024);
}

// Round 5
// 258.714 us; speedup vs baseline: 1.3002x; 1.3002x over previous
//
#include <hip/hip_runtime.h>

typedef __bf16 bf16;
typedef __bf16 bf16x4 __attribute__((ext_vector_type(4)));
typedef __bf16 bf16x8 __attribute__((ext_vector_type(8)));
typedef float f32x4 __attribute__((ext_vector_type(4)));

#define MFMA16(a, b, c) __builtin_amdgcn_mfma_f32_16x16x32_bf16(a, b, c, 0, 0, 0)

// async global->LDS DMA, 16B/lane; LDS dest = wave-uniform base + lane*16.
// (Exonerated: rounds 1-3 NaN was fp32-read-as-bf16, not this.)
__device__ __forceinline__ void lds_load16(void* lds, const void* g) {
  __builtin_amdgcn_global_load_lds(
      (const __attribute__((address_space(1))) unsigned int*)g,
      (__attribute__((address_space(3))) unsigned int*)lds, 16, 0, 0);
}

// fp32 -> bf16 bulk convert
__global__ void cvt(const float* __restrict__ in, bf16* __restrict__ out,
                    int n4) {
  const int i = blockIdx.x * blockDim.x + threadIdx.x;
  if (i < n4) {
    const float4 v = ((const float4*)in)[i];
    bf16x4 o;
    o[0] = (bf16)v.x; o[1] = (bf16)v.y; o[2] = (bf16)v.z; o[3] = (bf16)v.w;
    ((bf16x4*)out)[i] = o;
  }
}

// C = A[M][K] * B[N][K]^T + bias[N]; bf16 in, fp32 accum. m97-style DMA staging.
// MODE 0: write float C (stride N) -> d_out.
// MODE 1: QKV epilogue (N=3072): col<1024 -> Qb[t][col]; col<2048 ->
//         Kb[t][col-1024]; col>=2048 -> VT[b][h][dh][t] (t=2048).
template <int MODE>
__global__ __launch_bounds__(256, 2) void gemm_bt(
    const bf16* __restrict__ A, const bf16* __restrict__ B,
    const float* __restrict__ bias, float* __restrict__ Cf,
    bf16* __restrict__ Qb, bf16* __restrict__ Kb, bf16* __restrict__ VT,
    int N, int K) {
  __shared__ bf16 As[128][64];
  __shared__ bf16 Bs[128][64];
  const int tid = threadIdx.x;
  const int w = tid >> 6, lane = tid & 63;
  const int l15 = lane & 15, quad = lane >> 4;
  const int lr = lane >> 3;       // row within 8-row DMA chunk
  const int lc = (lane & 7) * 8;  // elem col within 64-col tile
  const int bn = blockIdx.x, bm = blockIdx.y;
  const int wm = (w >> 1) * 64, wn = (w & 1) * 64;

  const bf16* Abase = A + (size_t)(bm * 128) * K;
  const bf16* Bbase = B + (size_t)(bn * 128) * K;

  f32x4 acc[4][4] = {};

  for (int k0 = 0; k0 < K; k0 += 64) {
#pragma unroll
    for (int c = 0; c < 4; ++c) {
      const int row = w * 32 + c * 8;
      lds_load16(&As[row][0], Abase + (size_t)(row + lr) * K + k0 + lc);
      lds_load16(&Bs[row][0], Bbase + (size_t)(row + lr) * K + k0 + lc);
    }
    __syncthreads();
#pragma unroll
    for (int kk = 0; kk < 64; kk += 32) {
      bf16x8 am[4], bnf[4];
#pragma unroll
      for (int i = 0; i < 4; ++i)
        am[i] = *(const bf16x8*)&As[wm + i * 16 + l15][kk + quad * 8];
#pragma unroll
      for (int j = 0; j < 4; ++j)
        bnf[j] = *(const bf16x8*)&Bs[wn + j * 16 + l15][kk + quad * 8];
#pragma unroll
      for (int i = 0; i < 4; ++i)
#pragma unroll
        for (int j = 0; j < 4; ++j)
          acc[i][j] = MFMA16(am[i], bnf[j], acc[i][j]);
    }
    __syncthreads();
  }

  // epilogue: C/D layout col=lane&15, row=quad*4+reg
#pragma unroll
  for (int j = 0; j < 4; ++j) {
    const int gcol = bn * 128 + wn + j * 16 + l15;
    const float bv = bias[gcol];
#pragma unroll
    for (int i = 0; i < 4; ++i) {
#pragma unroll
      for (int r = 0; r < 4; ++r) {
        const int grow = bm * 128 + wm + i * 16 + quad * 4 + r;
        const float v = acc[i][j][r] + bv;
        if (MODE == 0) {
          Cf[(size_t)grow * N + gcol] = v;
        } else {
          if (gcol < 1024) {
            Qb[(size_t)grow * 1024 + gcol] = (bf16)v;
          } else if (gcol < 2048) {
            Kb[(size_t)grow * 1024 + (gcol - 1024)] = (bf16)v;
          } else {
            const int b = grow >> 11, t = grow & 2047;
            const int hh = (gcol >> 6) & 15, dh = gcol & 63;
            VT[(size_t)((b * 16 + hh) * 64 + dh) * 2048 + t] = (bf16)v;
          }
        }
      }
    }
  }
}

// Flash attention v2: one block per (b, h, 128-row q tile); 4 waves x 32 q rows.
// Padded LDS rows (72 elems = 144B = 36 banks -> 2-way conflicts = free).
// 2 barriers/iter; K/V tile register-prefetched across the compute phase.
// Qb/Kb: [token][1024] (head h at col h*64). VT: [b][h][dh][2048].
__global__ __launch_bounds__(256, 2) void attn(const bf16* __restrict__ Qb,
                                               const bf16* __restrict__ Kb,
                                               const bf16* __restrict__ VT,
                                               bf16* __restrict__ CTX) {
  __shared__ bf16 Qs[128][72];
  __shared__ bf16 Ks[64][72];
  __shared__ bf16 Vs[64][72];   // V^T tile: [dh][key]
  __shared__ bf16 Ps[128][72];  // wave-private row bands
  const int tid = threadIdx.x, w = tid >> 6, lane = tid & 63;
  const int l15 = lane & 15, quad = lane >> 4;
  const int blk = blockIdx.x;
  const int qt = blk & 15, h = (blk >> 4) & 15, b = blk >> 8;
  const int q0 = qt * 128;

  const bf16* qwave = Qb + (size_t)(b * 2048 + q0 + w * 32) * 1024 + h * 64;
  const bf16* kbase = Kb + (size_t)(b * 2048) * 1024 + h * 64;
  const bf16* vbase = VT + (size_t)((b * 16 + h) * 64) * 2048;

  // stage this wave's 32 Q rows (wave-private -> no barrier needed here)
#pragma unroll
  for (int c = 0; c < 4; ++c) {
    const int chunk = c * 64 + lane;  // 256 chunks = 32 rows x 8
    const int row = chunk >> 3, col = (chunk & 7) << 3;
    *(bf16x8*)&Qs[w * 32 + row][col] =
        *(const bf16x8*)&qwave[(size_t)row * 1024 + col];
  }

  // staging chunk mapping for 64x64 K/V tiles: 512 chunks over 256 threads
  const int c0 = tid, c1 = tid + 256;
  const int r0 = c0 >> 3, col0 = (c0 & 7) << 3;
  const int r1 = c1 >> 3, col1 = (c1 & 7) << 3;

  // preload first K/V tile into registers
  bf16x8 kreg0 = *(const bf16x8*)&kbase[(size_t)r0 * 1024 + col0];
  bf16x8 kreg1 = *(const bf16x8*)&kbase[(size_t)r1 * 1024 + col1];
  bf16x8 vreg0 = *(const bf16x8*)&vbase[(size_t)r0 * 2048 + col0];
  bf16x8 vreg1 = *(const bf16x8*)&vbase[(size_t)r1 * 2048 + col1];

  float m_run[2][4], l_run[2][4];
#pragma unroll
  for (int i = 0; i < 2; ++i)
#pragma unroll
    for (int r = 0; r < 4; ++r) { m_run[i][r] = -1e30f; l_run[i][r] = 0.f; }
  f32x4 o[2][4] = {};

  for (int kt = 0; kt < 2048; kt += 64) {
    *(bf16x8*)&Ks[r0][col0] = kreg0;
    *(bf16x8*)&Ks[r1][col1] = kreg1;
    *(bf16x8*)&Vs[r0][col0] = vreg0;
    *(bf16x8*)&Vs[r1][col1] = vreg1;
    __syncthreads();  // K/V tile visible to all waves

    // prefetch next tile into registers (latency hides under compute)
    if (kt < 2048 - 64) {
      const int nt = kt + 64;
      kreg0 = *(const bf16x8*)&kbase[(size_t)(nt + r0) * 1024 + col0];
      kreg1 = *(const bf16x8*)&kbase[(size_t)(nt + r1) * 1024 + col1];
      vreg0 = *(const bf16x8*)&vbase[(size_t)r0 * 2048 + nt + col0];
      vreg1 = *(const bf16x8*)&vbase[(size_t)r1 * 2048 + nt + col1];
    }

    // S = Q K^T : 2 tiles of 16 q rows x 64 keys
    f32x4 s[2][4] = {};
#pragma unroll
    for (int kk = 0; kk < 64; kk += 32) {
      bf16x8 aq[2], bk[4];
#pragma unroll
      for (int i = 0; i < 2; ++i)
        aq[i] = *(const bf16x8*)&Qs[w * 32 + i * 16 + l15][kk + quad * 8];
#pragma unroll
      for (int j = 0; j < 4; ++j)
        bk[j] = *(const bf16x8*)&Ks[j * 16 + l15][kk + quad * 8];
#pragma unroll
      for (int i = 0; i < 2; ++i)
#pragma unroll
        for (int j = 0; j < 4; ++j)
          s[i][j] = MFMA16(aq[i], bk[j], s[i][j]);
    }

    // online softmax per q row (row = i*16 + quad*4 + r)
#pragma unroll
    for (int i = 0; i < 2; ++i) {
#pragma unroll
      for (int r = 0; r < 4; ++r) {
        float v = fmaxf(fmaxf(s[i][0][r], s[i][1][r]),
                        fmaxf(s[i][2][r], s[i][3][r])) * 0.125f;
#pragma unroll
        for (int off = 1; off < 16; off <<= 1) v = fmaxf(v, __shfl_xor(v, off));
        const float mnew = fmaxf(m_run[i][r], v);
        const float alpha = __expf(m_run[i][r] - mnew);
        float sum = 0.f;
#pragma unroll
        for (int j = 0; j < 4; ++j) {
          const float p = __expf(s[i][j][r] * 0.125f - mnew);
          s[i][j][r] = p;
          sum += p;
        }
#pragma unroll
        for (int off = 1; off < 16; off <<= 1) sum += __shfl_xor(sum, off);
        l_run[i][r] = l_run[i][r] * alpha + sum;
        m_run[i][r] = mnew;
        // P: C-layout -> LDS (wave-private rows; no barrier), rescale O
#pragma unroll
        for (int j = 0; j < 4; ++j) {
          Ps[w * 32 + i * 16 + quad * 4 + r][j * 16 + l15] = (bf16)s[i][j][r];
          o[i][j][r] *= alpha;
        }
      }
    }

    // O += P * V  (V^T tile [dh][key] -> contiguous B frags)
#pragma unroll
    for (int kk = 0; kk < 64; kk += 32) {
      bf16x8 ap[2], bv[4];
#pragma unroll
      for (int i = 0; i < 2; ++i)
        ap[i] = *(const bf16x8*)&Ps[w * 32 + i * 16 + l15][kk + quad * 8];
#pragma unroll
      for (int j = 0; j < 4; ++j)
        bv[j] = *(const bf16x8*)&Vs[j * 16 + l15][kk + quad * 8];
#pragma unroll
      for (int i = 0; i < 2; ++i)
#pragma unroll
        for (int j = 0; j < 4; ++j)
          o[i][j] = MFMA16(ap[i], bv[j], o[i][j]);
    }
    __syncthreads();  // all waves done with Ks/Vs before next ds_write
  }

#pragma unroll
  for (int i = 0; i < 2; ++i)
#pragma unroll
    for (int r = 0; r < 4; ++r) {
      const float inv = 1.f / l_run[i][r];
      const size_t rowoff =
          (size_t)(b * 2048 + q0 + w * 32 + i * 16 + quad * 4 + r) * 1024 +
          h * 64;
#pragma unroll
      for (int j = 0; j < 4; ++j)
        CTX[rowoff + j * 16 + l15] = (bf16)(o[i][j][r] * inv);
    }
}

extern "C" void kernel_launch(void* const* d_in, const int* in_sizes, int n_in,
                              void* d_out, int out_size, void* d_ws,
                              size_t ws_size, hipStream_t stream) {
  const float* x = (const float*)d_in[0];      // [2,2048,1024] fp32
  const float* qkv_w = (const float*)d_in[1];  // [3072,1024] fp32
  const float* qkv_b = (const float*)d_in[2];  // [3072] fp32
  const float* out_w = (const float*)d_in[3];  // [1024,1024] fp32
  const float* out_b = (const float*)d_in[4];  // [1024] fp32
  float* out = (float*)d_out;                  // [2,2048,1024] fp32

  // ws (bf16): xb 8MB | wqkv 6MB | wout 2MB | qb 8 | kb 8 | vt 8 | ctx 8 = 48MB
  bf16* xb = (bf16*)d_ws;                   // [4096][1024]
  bf16* wqkv = xb + (size_t)4096 * 1024;    // [3072][1024]
  bf16* wout = wqkv + (size_t)3072 * 1024;  // [1024][1024]
  bf16* qb = wout + (size_t)1024 * 1024;    // [4096][1024]
  bf16* kb = qb + (size_t)4096 * 1024;      // [4096][1024]
  bf16* vt = kb + (size_t)4096 * 1024;      // [2][16][64][2048]
  bf16* ctx = vt + (size_t)4096 * 1024;     // [4096][1024]

  cvt<<<(4096 * 1024 / 4 + 255) / 256, 256, 0, stream>>>(x, xb, 4096 * 1024 / 4);
  cvt<<<(3072 * 1024 / 4 + 255) / 256, 256, 0, stream>>>(qkv_w, wqkv,
                                                         3072 * 1024 / 4);
  cvt<<<(1024 * 1024 / 4 + 255) / 256, 256, 0, stream>>>(out_w, wout,
                                                         1024 * 1024 / 4);

  gemm_bt<1><<<dim3(24, 32), 256, 0, stream>>>(xb, wqkv, qkv_b, nullptr, qb,
                                               kb, vt, 3072, 1024);
  attn<<<512, 256, 0, stream>>>(qb, kb, vt, ctx);
  gemm_bt<0><<<dim3(8, 32), 256, 0, stream>>>(ctx, wout, out_b, out, nullptr,
                                              nullptr, nullptr, 1024, 1024);
}

// Round 6
// 215.937 us; speedup vs baseline: 1.5578x; 1.1981x over previous
//
#include <hip/hip_runtime.h>

typedef __bf16 bf16;
typedef __bf16 bf16x4 __attribute__((ext_vector_type(4)));
typedef __bf16 bf16x8 __attribute__((ext_vector_type(8)));
typedef float f32x4 __attribute__((ext_vector_type(4)));

#define MFMA16(a, b, c) __builtin_amdgcn_mfma_f32_16x16x32_bf16(a, b, c, 0, 0, 0)

// async global->LDS DMA, 16B/lane; LDS dest = wave-uniform base + lane*16.
__device__ __forceinline__ void lds_load16(void* lds, const void* g) {
  __builtin_amdgcn_global_load_lds(
      (const __attribute__((address_space(1))) unsigned int*)g,
      (__attribute__((address_space(3))) unsigned int*)lds, 16, 0, 0);
}

// fp32 -> bf16 bulk convert
__global__ void cvt(const float* __restrict__ in, bf16* __restrict__ out,
                    int n4) {
  const int i = blockIdx.x * blockDim.x + threadIdx.x;
  if (i < n4) {
    const float4 v = ((const float4*)in)[i];
    bf16x4 o;
    o[0] = (bf16)v.x; o[1] = (bf16)v.y; o[2] = (bf16)v.z; o[3] = (bf16)v.w;
    ((bf16x4*)out)[i] = o;
  }
}

// C = A[M][K] * B[N][K]^T + bias[N]; bf16 in, fp32 accum. m97-style DMA staging.
// MODE 0: write float C (stride N) -> d_out.
// MODE 1: QKV epilogue (N=3072): col<1024 -> Qb[t][col] (PRE-SCALED by 0.125);
//         col<2048 -> Kb[t][col-1024]; col>=2048 -> VT[b][h][dh][t] (t=2048).
template <int MODE>
__global__ __launch_bounds__(256, 2) void gemm_bt(
    const bf16* __restrict__ A, const bf16* __restrict__ B,
    const float* __restrict__ bias, float* __restrict__ Cf,
    bf16* __restrict__ Qb, bf16* __restrict__ Kb, bf16* __restrict__ VT,
    int N, int K) {
  __shared__ bf16 As[128][64];
  __shared__ bf16 Bs[128][64];
  const int tid = threadIdx.x;
  const int w = tid >> 6, lane = tid & 63;
  const int l15 = lane & 15, quad = lane >> 4;
  const int lr = lane >> 3;       // row within 8-row DMA chunk
  const int lc = (lane & 7) * 8;  // elem col within 64-col tile
  const int bn = blockIdx.x, bm = blockIdx.y;
  const int wm = (w >> 1) * 64, wn = (w & 1) * 64;

  const bf16* Abase = A + (size_t)(bm * 128) * K;
  const bf16* Bbase = B + (size_t)(bn * 128) * K;

  f32x4 acc[4][4] = {};

  for (int k0 = 0; k0 < K; k0 += 64) {
#pragma unroll
    for (int c = 0; c < 4; ++c) {
      const int row = w * 32 + c * 8;
      lds_load16(&As[row][0], Abase + (size_t)(row + lr) * K + k0 + lc);
      lds_load16(&Bs[row][0], Bbase + (size_t)(row + lr) * K + k0 + lc);
    }
    __syncthreads();
#pragma unroll
    for (int kk = 0; kk < 64; kk += 32) {
      bf16x8 am[4], bnf[4];
#pragma unroll
      for (int i = 0; i < 4; ++i)
        am[i] = *(const bf16x8*)&As[wm + i * 16 + l15][kk + quad * 8];
#pragma unroll
      for (int j = 0; j < 4; ++j)
        bnf[j] = *(const bf16x8*)&Bs[wn + j * 16 + l15][kk + quad * 8];
#pragma unroll
      for (int i = 0; i < 4; ++i)
#pragma unroll
        for (int j = 0; j < 4; ++j)
          acc[i][j] = MFMA16(am[i], bnf[j], acc[i][j]);
    }
    __syncthreads();
  }

  // epilogue: C/D layout col=lane&15, row=quad*4+reg
#pragma unroll
  for (int j = 0; j < 4; ++j) {
    const int gcol = bn * 128 + wn + j * 16 + l15;
    const float bv = bias[gcol];
#pragma unroll
    for (int i = 0; i < 4; ++i) {
#pragma unroll
      for (int r = 0; r < 4; ++r) {
        const int grow = bm * 128 + wm + i * 16 + quad * 4 + r;
        const float v = acc[i][j][r] + bv;
        if (MODE == 0) {
          Cf[(size_t)grow * N + gcol] = v;
        } else {
          if (gcol < 1024) {
            Qb[(size_t)grow * 1024 + gcol] = (bf16)(v * 0.125f);  // fold scale
          } else if (gcol < 2048) {
            Kb[(size_t)grow * 1024 + (gcol - 1024)] = (bf16)v;
          } else {
            const int b = grow >> 11, t = grow & 2047;
            const int hh = (gcol >> 6) & 15, dh = gcol & 63;
            VT[(size_t)((b * 16 + hh) * 64 + dh) * 2048 + t] = (bf16)v;
          }
        }
      }
    }
  }
}

// Flash attention v3 — transposed-score design.
// One block per (b, h, 128-row q tile); 8 waves x 16 q rows. Q in registers.
// S^T = K Q^T  (rows=key on regs, cols=q on lanes)  -> softmax is in-lane.
// O^T = V^T P^T (rows=dh on regs, cols=q on lanes)  -> alpha/1/l lane-local.
// Qb pre-scaled by 0.125. Kb: [token][1024], VT: [b][h][dh][2048].
__global__ __launch_bounds__(512, 4) void attn(const bf16* __restrict__ Qb,
                                               const bf16* __restrict__ Kb,
                                               const bf16* __restrict__ VT,
                                               bf16* __restrict__ CTX) {
  __shared__ bf16 Ks[64][72];   // [key][dh]
  __shared__ bf16 Vs[64][72];   // V^T tile: [dh][key]
  __shared__ bf16 Ps[128][72];  // P: [q][key], wave-private 16-row bands
  const int tid = threadIdx.x, w = tid >> 6, lane = tid & 63;
  const int l15 = lane & 15, quad = lane >> 4;
  const int blk = blockIdx.x;
  const int qt = blk & 15, h = (blk >> 4) & 15, b = blk >> 8;
  const int q0 = qt * 128;

  const bf16* kbase = Kb + (size_t)(b * 2048) * 1024 + h * 64;
  const bf16* vbase = VT + (size_t)((b * 16 + h) * 64) * 2048;

  // Q fragments (B-operand, wave-private, registers only): lane q=l15
  const bf16* qrow =
      Qb + (size_t)(b * 2048 + q0 + w * 16 + l15) * 1024 + h * 64;
  const bf16x8 bq0 = *(const bf16x8*)&qrow[quad * 8];
  const bf16x8 bq1 = *(const bf16x8*)&qrow[32 + quad * 8];

  // K/V staging: 512 chunks of bf16x8 over 512 threads (1 each)
  const int r0 = tid >> 3, col0 = (tid & 7) << 3;
  bf16x8 kreg = *(const bf16x8*)&kbase[(size_t)r0 * 1024 + col0];
  bf16x8 vreg = *(const bf16x8*)&vbase[(size_t)r0 * 2048 + col0];

  float m_run = -1e30f, l_run = 0.f;
  f32x4 o[4] = {};

  for (int kt = 0; kt < 2048; kt += 64) {
    *(bf16x8*)&Ks[r0][col0] = kreg;
    *(bf16x8*)&Vs[r0][col0] = vreg;
    __syncthreads();

    // prefetch next K/V tile (hides under compute)
    if (kt < 2048 - 64) {
      const int nt = kt + 64;
      kreg = *(const bf16x8*)&kbase[(size_t)(nt + r0) * 1024 + col0];
      vreg = *(const bf16x8*)&vbase[(size_t)r0 * 2048 + nt + col0];
    }

    // S^T = K Q^T : rows = 64 keys (4 tiles), cols = 16 q
    f32x4 s[4] = {};
#pragma unroll
    for (int j = 0; j < 4; ++j) {
      const bf16x8 ak0 = *(const bf16x8*)&Ks[j * 16 + l15][quad * 8];
      s[j] = MFMA16(ak0, bq0, s[j]);
      const bf16x8 ak1 = *(const bf16x8*)&Ks[j * 16 + l15][32 + quad * 8];
      s[j] = MFMA16(ak1, bq1, s[j]);
    }

    // online softmax, q = l15 (replicated across quads), keys on regs
    float pm = s[0][0];
#pragma unroll
    for (int j = 0; j < 4; ++j)
#pragma unroll
      for (int r = 0; r < 4; ++r) pm = fmaxf(pm, s[j][r]);
    pm = fmaxf(pm, __shfl_xor(pm, 16));
    pm = fmaxf(pm, __shfl_xor(pm, 32));
    const float mnew = fmaxf(m_run, pm);
    const float alpha = __expf(m_run - mnew);
    float sum = 0.f;
#pragma unroll
    for (int j = 0; j < 4; ++j)
#pragma unroll
      for (int r = 0; r < 4; ++r) {
        const float p = __expf(s[j][r] - mnew);
        s[j][r] = p;
        sum += p;
      }
    sum += __shfl_xor(sum, 16);
    sum += __shfl_xor(sum, 32);
    l_run = l_run * alpha + sum;
    m_run = mnew;

    // O^T rescale (cols = q = l15: lane-local alpha)
#pragma unroll
    for (int j = 0; j < 4; ++j)
#pragma unroll
      for (int r = 0; r < 4; ++r) o[j][r] *= alpha;

    // P store: S^T C-layout -> Ps[q][key] (wave-private rows, b64 packed)
#pragma unroll
    for (int j = 0; j < 4; ++j) {
      bf16x4 pk;
#pragma unroll
      for (int r = 0; r < 4; ++r) pk[r] = (bf16)s[j][r];
      *(bf16x4*)&Ps[w * 16 + l15][j * 16 + quad * 4] = pk;
    }

    // O^T += V^T P^T : A = Vs[dh][key], B = Ps[q][key]
#pragma unroll
    for (int kk = 0; kk < 64; kk += 32) {
      const bf16x8 bp = *(const bf16x8*)&Ps[w * 16 + l15][kk + quad * 8];
#pragma unroll
      for (int j = 0; j < 4; ++j) {
        const bf16x8 av = *(const bf16x8*)&Vs[j * 16 + l15][kk + quad * 8];
        o[j] = MFMA16(av, bp, o[j]);
      }
    }
    __syncthreads();  // all waves done with Ks/Vs before next ds_write
  }

  // write O^T -> ctx[token][1024]: lane q=l15 owns token; dh = j*16+quad*4+r
  const float inv = 1.f / l_run;
  bf16* crow = CTX + (size_t)(b * 2048 + q0 + w * 16 + l15) * 1024 + h * 64;
#pragma unroll
  for (int j = 0; j < 4; ++j) {
    bf16x4 ov;
#pragma unroll
    for (int r = 0; r < 4; ++r) ov[r] = (bf16)(o[j][r] * inv);
    *(bf16x4*)&crow[j * 16 + quad * 4] = ov;
  }
}

extern "C" void kernel_launch(void* const* d_in, const int* in_sizes, int n_in,
                              void* d_out, int out_size, void* d_ws,
                              size_t ws_size, hipStream_t stream) {
  const float* x = (const float*)d_in[0];      // [2,2048,1024] fp32
  const float* qkv_w = (const float*)d_in[1];  // [3072,1024] fp32
  const float* qkv_b = (const float*)d_in[2];  // [3072] fp32
  const float* out_w = (const float*)d_in[3];  // [1024,1024] fp32
  const float* out_b = (const float*)d_in[4];  // [1024] fp32
  float* out = (float*)d_out;                  // [2,2048,1024] fp32

  // ws (bf16): xb 8MB | wqkv 6MB | wout 2MB | qb 8 | kb 8 | vt 8 | ctx 8 = 48MB
  bf16* xb = (bf16*)d_ws;                   // [4096][1024]
  bf16* wqkv = xb + (size_t)4096 * 1024;    // [3072][1024]
  bf16* wout = wqkv + (size_t)3072 * 1024;  // [1024][1024]
  bf16* qb = wout + (size_t)1024 * 1024;    // [4096][1024] pre-scaled 0.125
  bf16* kb = qb + (size_t)4096 * 1024;      // [4096][1024]
  bf16* vt = kb + (size_t)4096 * 1024;      // [2][16][64][2048]
  bf16* ctx = vt + (size_t)4096 * 1024;     // [4096][1024]

  cvt<<<(4096 * 1024 / 4 + 255) / 256, 256, 0, stream>>>(x, xb, 4096 * 1024 / 4);
  cvt<<<(3072 * 1024 / 4 + 255) / 256, 256, 0, stream>>>(qkv_w, wqkv,
                                                         3072 * 1024 / 4);
  cvt<<<(1024 * 1024 / 4 + 255) / 256, 256, 0, stream>>>(out_w, wout,
                                                         1024 * 1024 / 4);

  gemm_bt<1><<<dim3(24, 32), 256, 0, stream>>>(xb, wqkv, qkv_b, nullptr, qb,
                                               kb, vt, 3072, 1024);
  attn<<<512, 512, 0, stream>>>(qb, kb, vt, ctx);
  gemm_bt<0><<<dim3(8, 32), 256, 0, stream>>>(ctx, wout, out_b, out, nullptr,
                                              nullptr, nullptr, 1024, 1024);
}